// Round 10
// baseline (160.179 us; speedup 1.0000x reference)
//
#include <hip/hip_runtime.h>

#define NB 8      // NUM_BLOCK
#define NT 500    // NUM_FRAME
#define NF 257    // NUM_BIN
#define NC 8      // NUM_CH
#define NNUL 4    // NUM_NULL
#define LOWF 5
#define HIGHF 70
#define S_CHUNK 8
#define WARM 4
#define N_CHUNK 63   // ceil(NT / S_CHUNK)
#define AL 0.35f

__device__ __forceinline__ float dot4(const float4& a, const float4& b) {
    return a.x*b.x + a.y*b.y + a.z*b.z + a.w*b.w;
}
__device__ __forceinline__ float dot8(const float4& a0, const float4& a1,
                                      const float4& b0, const float4& b1) {
    return dot4(a0, b0) + dot4(a1, b1);
}
__device__ __forceinline__ float fast_rcp(float v) {
#if __has_builtin(__builtin_amdgcn_rcpf)
    return __builtin_amdgcn_rcpf(v);
#else
    return 1.0f / v;
#endif
}
__device__ __forceinline__ float fast_sqrt(float v) {
#if __has_builtin(__builtin_amdgcn_sqrtf)
    return __builtin_amdgcn_sqrtf(v);
#else
    return sqrtf(v);
#endif
}
__device__ __forceinline__ float clamp01(float v) {
#if __has_builtin(__builtin_amdgcn_fmed3f)
    return __builtin_amdgcn_fmed3f(v, 0.01f, 1.0f);   // v>=0 here: med3 == clip
#else
    return fminf(fmaxf(v, 0.01f), 1.0f);
#endif
}

// R10 = R9 + depth-2 ping-pong prefetch (single-variable change).
// R9 post-mortem: halving VMEM insts gave only -1us (48.4us) -> L1 request
// traffic was never the constraint. Remaining stall ~30us with VALU 36%,
// HBM 18%: FETCH 39MB of 66MB unique -> ~60% of x is HBM-latency (~900cy).
// All 16 waves run the same loop from a common barrier; issue arbitration
// phase-locks them -> all exhaust compute together and the HBM-latency tail
// stalls every wave at once (TLP can't help). Fix: double load->use distance
// via depth-2 ping-pong (La/Lb), ~2 frame-bodies of cover. Frames/chunk are
// always even (8 or 12), so no tail iteration. VGPR-neutral vs R9's
// prefetch+copy (~64); R3's ping-pong with more live state was 64.
// DO NOT raise launch_bounds 2nd arg ((1024,8) => 32-VGPR budget => full
// spill, 563MB writes, 306us in R5). Grid stays 504 (S=12 regressed: R8).
// Kept from R9: own-parity-only loads (4 null-weight vectors, scalar quad
// exchange Q/Y), marching pointers, wave-15 extra path (f=256), fast
// rcp/sqrt/med3, quad-neighbor pw, predicated tr/ti stores, deferred-ratio
// epilogue (2 barriers/block).
__global__ __launch_bounds__(1024, 4) void dcf_fused_kernel(
    const float* __restrict__ x,           // (NB,NT,2,NF,NC) fp32
    const int* __restrict__ beam_id,       // (NB,)
    const float* __restrict__ targ_w,      // (8,2,NF,NC) fp32
    const float* __restrict__ null_w,      // (8,NNUL,2,NF,NC) fp32
    float* __restrict__ out)               // fp32: dcf (NB,NT,NF,NNUL) then targ (NB,NT,2,NF)
{
    const int tid = threadIdx.x;
    const int bid = blockIdx.x;
    const int b  = bid & 7;
    const int k  = bid >> 3;
    const int t0 = k * S_CHUNK;
    const int te = min(NT, t0 + S_CHUNK);
    int ts = t0 - WARM; if (ts < 0) ts = 0;

    const int f = tid >> 2;                // 0..255
    const int n = tid & 3;
    const int wid = tid >> 6;
    const int lane = tid & 63;
    const bool extra = (tid >= 1020);      // f=255 quad of wave 15 also does f=256

    __shared__ float s_w256[16 + 4 * 16];       // f=256 weights: twr,twi then per-n nwr,nwi
    __shared__ float s_part[S_CHUNK][25];       // per-frame ratio partials (waves 0..4 write)
    __shared__ float s_dcf[S_CHUNK][1028];      // pre-ratio dcf: [frame][tid], +4 for f=256

    const int beam = beam_id[b];
    const int pA = n & 1;                  // lane's parity: 0=real(even n), 1=imag(odd n)
    const int offA = pA * (NF * NC);       // own-parity plane offset
    const int offB = (1 - pA) * (NF * NC); // other-parity plane offset (weights only)
    const int psel = (n == 1 || n == 2) ? 1 : 0;   // targ part for this lane's partial
    const float nsign = pA ? -1.f : 1.f;

    // weights in registers: 10 float4 per thread (targ + 4 null vectors)
    float4 tw0, tw1, w10, w11, w20, w21, w30, w31, w40, w41;
    {
        const float* tp = targ_w + ((size_t)(beam * 2 + psel) * NF + f) * NC;
        tw0 = *(const float4*)(tp);  tw1 = *(const float4*)(tp + 4);
        const float* qp  = null_w + ((size_t)((beam * NNUL + n) * 2) * NF + f) * NC;
        const float* qpx = null_w + ((size_t)((beam * NNUL + (n ^ 1)) * 2) * NF + f) * NC;
        w10 = *(const float4*)(qp  + offA);  w11 = *(const float4*)(qp  + offA + 4);
        w20 = *(const float4*)(qp  + offB);  w21 = *(const float4*)(qp  + offB + 4);
        w30 = *(const float4*)(qpx + offA);  w31 = *(const float4*)(qpx + offA + 4);
        w40 = *(const float4*)(qpx + offB);  w41 = *(const float4*)(qpx + offB + 4);
    }
    if (tid < 16) {
        int p = tid >> 3, c = tid & 7;
        s_w256[tid] = targ_w[((size_t)(beam * 2 + p) * NF + 256) * NC + c];
    } else if (tid < 80) {
        int i = tid - 16;
        int nn = i >> 4, p = (i >> 3) & 1, c = i & 7;
        s_w256[tid] = null_w[((size_t)((beam * NNUL + nn) * 2 + p) * NF + 256) * NC + c];
    }
    __syncthreads();   // barrier 1 of 2 (weights visible)

    float phi_r = 0.f, phi_i = 0.f, psd = 0.f;
    float phi_r2 = 0.f, phi_i2 = 0.f, psd2 = 0.f;
    const float a = AL, oma = 1.0f - AL;
    const int rl = 2 * NF * NC;            // 4112 floats per (b,t)
    const bool in_red = (f >= LOWF) && (f < HIGHF);   // waves 0..4 only

    // own-parity plane pointers
    const float* xp0 = x + (size_t)(b * NT + ts) * rl + f * NC + offA;
    const float* xpe = x + (size_t)(b * NT + ts) * rl + 256 * NC + offA;  // f=256 row (extra)

    float* outT = out + (size_t)NB * NT * NF * NNUL;
    float* poT = outT + ((size_t)(b * NT + t0) * 2 + n) * NF + f;  // used when n<2
    float* sdp = &s_dcf[0][tid];
    float* spp = &s_part[0][wid * 5];

    auto frame = [&](const int t, const float4& A0, const float4& A1) {
        // targ dots via quad butterfly (own parity only):
        // n0: xr.twr  n1: xi.twi  n2: xr.twi  n3: xi.twr
        const float d = dot8(A0, A1, tw0, tw1);
        const float e = __shfl_xor(d, 1);
        const float u = (n < 2) ? ((n == 0) ? (d - e) : (e - d)) : (d + e);
        const float v = __shfl_xor(u, 2);
        const float tr = (n < 2) ? u : v;
        const float ti = (n < 2) ? v : u;

        // null dots: own-data x 4 weight sets, scalar quad exchange
        const float P  = dot8(A0, A1, w10, w11);   // A.W[n,p]
        const float X  = dot8(A0, A1, w20, w21);   // A.W[n,1-p]
        const float s3 = dot8(A0, A1, w30, w31);   // A.W[n^1,p]   -> neighbor's Q
        const float s4 = dot8(A0, A1, w40, w41);   // A.W[n^1,1-p] -> neighbor's Y
        const float Q  = __shfl_xor(s3, 1);
        const float Y  = __shfl_xor(s4, 1);
        const float nr = nsign * (P - Q);
        const float ni = X + Y;

        // pw: |A|^2 here; quad-neighbor (n^1) holds the other parity
        float sq = dot4(A0, A0) + dot4(A1, A1);
        sq += __shfl_xor(sq, 1);
        const float pw = sq * 0.125f;

        if (t == 0) {  // exact asymmetric init from the reference
            phi_r = oma * tr * nr + ti * ni;
            phi_i = oma * ti * nr - tr * ni;
            psd   = oma * pw;
        } else {
            phi_r = a * phi_r + oma * (tr * nr + ti * ni);
            phi_i = a * phi_i + oma * (ti * nr - tr * ni);
            psd   = a * psd + oma * pw;
        }

        // f=256 on the f=255 quad of wave 15: weights from LDS, x via xpe
        float tr2 = 0.f, ti2 = 0.f;
        if (extra) {
            const float4 eA0 = *(const float4*)(xpe);
            const float4 eA1 = *(const float4*)(xpe + 4);
            const float4 etw0 = *(const float4*)&s_w256[psel * 8];
            const float4 etw1 = *(const float4*)&s_w256[psel * 8 + 4];
            const float* nq  = &s_w256[16 + n * 16];
            const float* nqx = &s_w256[16 + (n ^ 1) * 16];
            const float4 e10 = *(const float4*)(nq  + pA * 8);
            const float4 e11 = *(const float4*)(nq  + pA * 8 + 4);
            const float4 e20 = *(const float4*)(nq  + (1 - pA) * 8);
            const float4 e21 = *(const float4*)(nq  + (1 - pA) * 8 + 4);
            const float4 e30 = *(const float4*)(nqx + pA * 8);
            const float4 e31 = *(const float4*)(nqx + pA * 8 + 4);
            const float4 e40 = *(const float4*)(nqx + (1 - pA) * 8);
            const float4 e41 = *(const float4*)(nqx + (1 - pA) * 8 + 4);
            const float d2 = dot8(eA0, eA1, etw0, etw1);
            const float e2 = __shfl_xor(d2, 1);
            const float u2 = (n < 2) ? ((n == 0) ? (d2 - e2) : (e2 - d2)) : (d2 + e2);
            const float v2 = __shfl_xor(u2, 2);
            tr2 = (n < 2) ? u2 : v2;
            ti2 = (n < 2) ? v2 : u2;
            const float P2  = dot8(eA0, eA1, e10, e11);
            const float X2  = dot8(eA0, eA1, e20, e21);
            const float s32 = dot8(eA0, eA1, e30, e31);
            const float s42 = dot8(eA0, eA1, e40, e41);
            const float Q2  = __shfl_xor(s32, 1);
            const float Y2  = __shfl_xor(s42, 1);
            const float nr2 = nsign * (P2 - Q2);
            const float ni2 = X2 + Y2;
            float sq2 = dot4(eA0, eA0) + dot4(eA1, eA1);
            sq2 += __shfl_xor(sq2, 1);
            const float pw2 = sq2 * 0.125f;
            if (t == 0) {
                phi_r2 = oma * tr2 * nr2 + ti2 * ni2;
                phi_i2 = oma * ti2 * nr2 - tr2 * ni2;
                psd2   = oma * pw2;
            } else {
                phi_r2 = a * phi_r2 + oma * (tr2 * nr2 + ti2 * ni2);
                phi_i2 = a * phi_i2 + oma * (ti2 * nr2 - tr2 * ni2);
                psd2   = a * psd2 + oma * pw2;
            }
        }
        xpe += rl;

        if (t >= t0) {
            const float phi = fast_sqrt(phi_r * phi_r + phi_i * phi_i);
            const float dcfv = clamp01(phi * fast_rcp(psd + 1e-13f));
            if (n < 2) *poT = (n == 0) ? tr : ti;
            *sdp = dcfv;                                 // pre-ratio, own slot
            if (extra) {
                const float phi2 = fast_sqrt(phi_r2 * phi_r2 + phi_i2 * phi_i2);
                const float dcf2v = clamp01(phi2 * fast_rcp(psd2 + 1e-13f));
                sdp[4] = dcf2v;                          // slot 1024+n (tid=1020+n)
                if (n < 2) poT[1] = (n == 0) ? tr2 : ti2;   // f=256 targ
            }
            // ratio partials: waves 0..4 hold f in [5,70); NO barrier here
            if (wid < 5) {
                float v_phi = in_red ? phi : 0.f;
                float v_psd = (in_red && n == 0) ? psd : 0.f;
                #pragma unroll
                for (int off = 4; off < 64; off <<= 1) {
                    v_phi += __shfl_xor(v_phi, off);
                    v_psd += __shfl_xor(v_psd, off);
                }
                if (lane < 4)  spp[lane] = v_phi;        // phi sum, n=lane
                if (lane == 0) spp[4]    = v_psd;        // psd sum
            }
            poT += 2 * NF; sdp += 1028; spp += 25;
        }
    };

    // depth-2 ping-pong prefetch; te-ts is always even (8 or 12)
    float4 La0 = *(const float4*)(xp0);
    float4 La1 = *(const float4*)(xp0 + 4);
    float4 Lb0 = *(const float4*)(xp0 + rl);
    float4 Lb1 = *(const float4*)(xp0 + rl + 4);
    const float* xpn = xp0 + 2 * (size_t)rl;
    for (int t = ts; t < te; t += 2) {
        frame(t, La0, La1);
        if (t + 2 < te) {
            La0 = *(const float4*)(xpn);
            La1 = *(const float4*)(xpn + 4);
            xpn += rl;
        }
        frame(t + 1, Lb0, Lb1);
        if (t + 3 < te) {
            Lb0 = *(const float4*)(xpn);
            Lb1 = *(const float4*)(xpn + 4);
            xpn += rl;
        }
    }

    __syncthreads();   // barrier 2 of 2: all frames' s_dcf + s_part visible

    // uniform epilogue: apply ratio, write final dcf for all output frames
    float* po = out + ((size_t)(b * NT + t0) * NF + f) * NNUL + n;
    const float* sdr = &s_dcf[0][tid];
    const float* spr = &s_part[0][0];
    const int nf = te - t0;
    for (int fr = 0; fr < nf; ++fr) {
        const int t = t0 + fr;
        float dcfv = sdr[0];
        float dcf2v = extra ? sdr[4] : 0.f;
        if (t >= 1) {
            const float pre = spr[4] + spr[9] + spr[14] + spr[19] + spr[24];
            const float aft = spr[n] + spr[5 + n] + spr[10 + n] + spr[15 + n] + spr[20 + n];
            const float ratio = clamp01(aft * fast_rcp(pre + 1e-10f));
            dcfv = fast_sqrt(dcfv * ratio);
            if (extra) dcf2v = fast_sqrt(dcf2v * ratio);
        }
        *po = dcfv;
        if (extra) po[NNUL] = dcf2v;                     // f=256 slot
        po += NF * NNUL; sdr += 1028; spr += 25;
    }
}

extern "C" void kernel_launch(void* const* d_in, const int* in_sizes, int n_in,
                              void* d_out, int out_size, void* d_ws, size_t ws_size,
                              hipStream_t stream) {
    const float* x       = (const float*)d_in[0];
    const int*   beam_id = (const int*)d_in[1];
    const float* targ_w  = (const float*)d_in[2];
    const float* null_w  = (const float*)d_in[3];
    float* out           = (float*)d_out;
    (void)d_ws; (void)ws_size;

    dcf_fused_kernel<<<dim3(NB * N_CHUNK), dim3(1024), 0, stream>>>(
        x, beam_id, targ_w, null_w, out);
}

// Round 11
// 126.965 us; speedup vs baseline: 1.2616x; 1.2616x over previous
//
#include <hip/hip_runtime.h>

#define NB 8      // NUM_BLOCK
#define NT 500    // NUM_FRAME
#define NF 257    // NUM_BIN
#define NC 8      // NUM_CH
#define NNUL 4    // NUM_NULL
#define LOWF 5
#define HIGHF 70
#define S_CHUNK 8
#define WARM 4
#define N_CHUNK 63   // ceil(NT / S_CHUNK)
#define AL 0.35f

__device__ __forceinline__ float dot4(const float4& a, const float4& b) {
    return a.x*b.x + a.y*b.y + a.z*b.z + a.w*b.w;
}
__device__ __forceinline__ float dot8(const float4& a0, const float4& a1,
                                      const float4& b0, const float4& b1) {
    return dot4(a0, b0) + dot4(a1, b1);
}
__device__ __forceinline__ float fast_rcp(float v) {
#if __has_builtin(__builtin_amdgcn_rcpf)
    return __builtin_amdgcn_rcpf(v);
#else
    return 1.0f / v;
#endif
}
__device__ __forceinline__ float fast_sqrt(float v) {
#if __has_builtin(__builtin_amdgcn_sqrtf)
    return __builtin_amdgcn_sqrtf(v);
#else
    return sqrtf(v);
#endif
}
__device__ __forceinline__ float clamp01(float v) {
#if __has_builtin(__builtin_amdgcn_fmed3f)
    return __builtin_amdgcn_fmed3f(v, 0.01f, 1.0f);   // v>=0 here: med3 == clip
#else
    return fminf(fmaxf(v, 0.01f), 1.0f);
#endif
}

// R11 = R9 skeleton + two critical-path fixes (NO new persistent registers).
// HARD-LEARNED REGISTER RULE (R5, R10): this body sits AT the 64-VGPR
// occupancy cliff; the compiler targets 64 and SPILLS excess (R10: ping-pong
// regs -> VGPR "64" + 28MB scratch writes, 78us). Never add persistent regs.
// R11 theory: VALU-issue model says ~20us; measured 48. Stall is the block
// critical path into the final barrier:
//  (1) wave 15's f=256 path loaded global x per frame and used it instantly
//      (~200-900cy exposed x12 frames; 15 waves wait on it at barrier 2).
//      Fix: pre-stage all <=12 f=256 rows (<=768B) into s_xe at init (48
//      lanes, 1 float4 each); in-loop reads become ds_read (~120cy, hidden).
//  (2) waves 0..4 ran a 10-op ds_swizzle serial chain (~600cy) per frame for
//      the [5,70) ratio sums. Fix: in-loop stores raw phi (s_dcf) + psd
//      (s_psd) only — uniform waves, no cross-lane ops; reduction runs ONCE
//      in epilogue phase 1, parallel on 8 waves; barrier; phase 2 computes
//      dcf = clamp(phi/psd) * ratio for all frames. Barriers 2 -> 3 (cheap).
// LDS 43KB (s_dcf 32KB + s_psd 8.3KB + misc) -> still 2 blocks/CU
// (wave-slot bound). Grid 504 x 1024 (S=8; S=12 starved TLP in R8).
// Kept from R9: own-parity loads + 4 null-weight vectors + scalar quad
// exchange, marching pointers, fast rcp/sqrt/med3, quad-neighbor pw,
// predicated tr/ti stores, depth-1 prefetch.
__global__ __launch_bounds__(1024, 4) void dcf_fused_kernel(
    const float* __restrict__ x,           // (NB,NT,2,NF,NC) fp32
    const int* __restrict__ beam_id,       // (NB,)
    const float* __restrict__ targ_w,      // (8,2,NF,NC) fp32
    const float* __restrict__ null_w,      // (8,NNUL,2,NF,NC) fp32
    float* __restrict__ out)               // fp32: dcf (NB,NT,NF,NNUL) then targ (NB,NT,2,NF)
{
    const int tid = threadIdx.x;
    const int bid = blockIdx.x;
    const int b  = bid & 7;
    const int k  = bid >> 3;
    const int t0 = k * S_CHUNK;
    const int te = min(NT, t0 + S_CHUNK);
    int ts = t0 - WARM; if (ts < 0) ts = 0;

    const int f = tid >> 2;                // 0..255
    const int n = tid & 3;
    const int wid = tid >> 6;
    const int lane = tid & 63;
    const bool extra = (tid >= 1020);      // f=255 quad of wave 15 also does f=256

    __shared__ float s_w256[16 + 4 * 16];       // f=256 weights
    __shared__ float s_xe[12 * 16];             // staged f=256 x rows: [frame][parity][8]
    __shared__ float s_part[S_CHUNK][25];       // ratio sums (epilogue phase 1 writes)
    __shared__ float s_psd[S_CHUNK][260];       // psd per (frame, f); [fr][256] = f=256
    __shared__ float s_dcf[S_CHUNK][1028];      // PHI per (frame, tid); [fr][1024+n] = f=256

    const int beam = beam_id[b];
    const int pA = n & 1;                  // lane's parity: 0=real(even n), 1=imag(odd n)
    const int offA = pA * (NF * NC);       // own-parity plane offset
    const int offB = (1 - pA) * (NF * NC); // other-parity plane offset (weights only)
    const int psel = (n == 1 || n == 2) ? 1 : 0;
    const float nsign = pA ? -1.f : 1.f;
    const int rl = 2 * NF * NC;            // 4112 floats per (b,t)

    // weights in registers: 10 float4 per thread (targ + 4 null vectors)
    float4 tw0, tw1, w10, w11, w20, w21, w30, w31, w40, w41;
    {
        const float* tp = targ_w + ((size_t)(beam * 2 + psel) * NF + f) * NC;
        tw0 = *(const float4*)(tp);  tw1 = *(const float4*)(tp + 4);
        const float* qp  = null_w + ((size_t)((beam * NNUL + n) * 2) * NF + f) * NC;
        const float* qpx = null_w + ((size_t)((beam * NNUL + (n ^ 1)) * 2) * NF + f) * NC;
        w10 = *(const float4*)(qp  + offA);  w11 = *(const float4*)(qp  + offA + 4);
        w20 = *(const float4*)(qp  + offB);  w21 = *(const float4*)(qp  + offB + 4);
        w30 = *(const float4*)(qpx + offA);  w31 = *(const float4*)(qpx + offA + 4);
        w40 = *(const float4*)(qpx + offB);  w41 = *(const float4*)(qpx + offB + 4);
    }
    if (tid < 16) {
        int p = tid >> 3, c = tid & 7;
        s_w256[tid] = targ_w[((size_t)(beam * 2 + p) * NF + 256) * NC + c];
    } else if (tid < 80) {
        int i = tid - 16;
        int nn = i >> 4, p = (i >> 3) & 1, c = i & 7;
        s_w256[tid] = null_w[((size_t)((beam * NNUL + nn) * 2 + p) * NF + 256) * NC + c];
    } else if (tid >= 128 && tid < 176) {
        // stage f=256 x rows for all frames of this chunk: 1 float4 per lane
        const int i = tid - 128;           // 0..47
        const int c = i >> 1, h = i & 1;   // chunk (frame,parity), float4 half
        const int fr = c >> 1, p = c & 1;
        if (fr < te - ts) {
            const float* src = x + (size_t)(b * NT + ts + fr) * rl
                             + p * (NF * NC) + 256 * NC + h * 4;
            *(float4*)&s_xe[fr * 16 + p * 8 + h * 4] = *(const float4*)src;
        }
    }
    __syncthreads();   // barrier 1 of 3 (weights + staged rows visible)

    float phi_r = 0.f, phi_i = 0.f, psd = 0.f;
    float phi_r2 = 0.f, phi_i2 = 0.f, psd2 = 0.f;
    const float a = AL, oma = 1.0f - AL;

    // own-parity plane marching pointer
    const float* xpa = x + (size_t)(b * NT + ts) * rl + f * NC + offA;
    float4 pA0 = *(const float4*)(xpa);
    float4 pA1 = *(const float4*)(xpa + 4);

    float* outT = out + (size_t)NB * NT * NF * NNUL;
    float* poT = outT + ((size_t)(b * NT + t0) * 2 + n) * NF + f;  // used when n<2
    float* sdp = &s_dcf[0][tid];
    float* spq = &s_psd[0][f];

    for (int t = ts; t < te; ++t) {
        const float4 A0 = pA0, A1 = pA1;
        xpa += rl;
        if (t + 1 < te) {
            pA0 = *(const float4*)(xpa);
            pA1 = *(const float4*)(xpa + 4);
        }

        // targ dots via quad butterfly (own parity only)
        const float d = dot8(A0, A1, tw0, tw1);
        const float e = __shfl_xor(d, 1);
        const float u = (n < 2) ? ((n == 0) ? (d - e) : (e - d)) : (d + e);
        const float v = __shfl_xor(u, 2);
        const float tr = (n < 2) ? u : v;
        const float ti = (n < 2) ? v : u;

        // null dots: own-data x 4 weight sets, scalar quad exchange
        const float P  = dot8(A0, A1, w10, w11);
        const float X  = dot8(A0, A1, w20, w21);
        const float s3 = dot8(A0, A1, w30, w31);
        const float s4 = dot8(A0, A1, w40, w41);
        const float Q  = __shfl_xor(s3, 1);
        const float Y  = __shfl_xor(s4, 1);
        const float nr = nsign * (P - Q);
        const float ni = X + Y;

        // pw: |A|^2 here; quad-neighbor holds the other parity
        float sq = dot4(A0, A0) + dot4(A1, A1);
        sq += __shfl_xor(sq, 1);
        const float pw = sq * 0.125f;

        if (t == 0) {  // exact asymmetric init from the reference
            phi_r = oma * tr * nr + ti * ni;
            phi_i = oma * ti * nr - tr * ni;
            psd   = oma * pw;
        } else {
            phi_r = a * phi_r + oma * (tr * nr + ti * ni);
            phi_i = a * phi_i + oma * (ti * nr - tr * ni);
            psd   = a * psd + oma * pw;
        }

        // f=256 on the f=255 quad of wave 15: x from LDS stage (no HBM stall)
        float tr2 = 0.f, ti2 = 0.f;
        if (extra) {
            const float* xe = &s_xe[(t - ts) * 16 + pA * 8];
            const float4 eA0 = *(const float4*)(xe);
            const float4 eA1 = *(const float4*)(xe + 4);
            const float4 etw0 = *(const float4*)&s_w256[psel * 8];
            const float4 etw1 = *(const float4*)&s_w256[psel * 8 + 4];
            const float* nq  = &s_w256[16 + n * 16];
            const float* nqx = &s_w256[16 + (n ^ 1) * 16];
            const float4 e10 = *(const float4*)(nq  + pA * 8);
            const float4 e11 = *(const float4*)(nq  + pA * 8 + 4);
            const float4 e20 = *(const float4*)(nq  + (1 - pA) * 8);
            const float4 e21 = *(const float4*)(nq  + (1 - pA) * 8 + 4);
            const float4 e30 = *(const float4*)(nqx + pA * 8);
            const float4 e31 = *(const float4*)(nqx + pA * 8 + 4);
            const float4 e40 = *(const float4*)(nqx + (1 - pA) * 8);
            const float4 e41 = *(const float4*)(nqx + (1 - pA) * 8 + 4);
            const float d2 = dot8(eA0, eA1, etw0, etw1);
            const float e2 = __shfl_xor(d2, 1);
            const float u2 = (n < 2) ? ((n == 0) ? (d2 - e2) : (e2 - d2)) : (d2 + e2);
            const float v2 = __shfl_xor(u2, 2);
            tr2 = (n < 2) ? u2 : v2;
            ti2 = (n < 2) ? v2 : u2;
            const float P2  = dot8(eA0, eA1, e10, e11);
            const float X2  = dot8(eA0, eA1, e20, e21);
            const float s32 = dot8(eA0, eA1, e30, e31);
            const float s42 = dot8(eA0, eA1, e40, e41);
            const float Q2  = __shfl_xor(s32, 1);
            const float Y2  = __shfl_xor(s42, 1);
            const float nr2 = nsign * (P2 - Q2);
            const float ni2 = X2 + Y2;
            float sq2 = dot4(eA0, eA0) + dot4(eA1, eA1);
            sq2 += __shfl_xor(sq2, 1);
            const float pw2 = sq2 * 0.125f;
            if (t == 0) {
                phi_r2 = oma * tr2 * nr2 + ti2 * ni2;
                phi_i2 = oma * ti2 * nr2 - tr2 * ni2;
                psd2   = oma * pw2;
            } else {
                phi_r2 = a * phi_r2 + oma * (tr2 * nr2 + ti2 * ni2);
                phi_i2 = a * phi_i2 + oma * (ti2 * nr2 - tr2 * ni2);
                psd2   = a * psd2 + oma * pw2;
            }
        }

        if (t >= t0) {
            const float phi = fast_sqrt(phi_r * phi_r + phi_i * phi_i);
            if (n < 2) *poT = (n == 0) ? tr : ti;
            *sdp = phi;                        // raw phi; dcf formed in epilogue
            if (n == 0) *spq = psd;            // s_psd[fr][f]
            if (extra) {
                const float phi2 = fast_sqrt(phi_r2 * phi_r2 + phi_i2 * phi_i2);
                sdp[4] = phi2;                 // slot 1024+n
                if (n == 0) spq[1] = psd2;     // s_psd[fr][256] (f=255 lane)
                if (n < 2) poT[1] = (n == 0) ? tr2 : ti2;
            }
            poT += 2 * NF; sdp += 1028; spq += 260;
        }
    }

    __syncthreads();   // barrier 2 of 3: all phi/psd slabs visible

    const int nf = te - t0;
    // epilogue phase 1: waves 0..7 reduce the [5,70) sums, one frame each
    if (wid < 8 && wid < nf && (t0 + wid) >= 1) {
        const int fr = wid;
        const float* sd = &s_dcf[fr][0];
        float vp = sd[20 + lane] + sd[84 + lane] + sd[148 + lane] + sd[212 + lane];
        if (lane < 4) vp += sd[276 + lane];          // tid 276..279 (f=69)
        const float* sp2 = &s_psd[fr][0];
        float vq = sp2[5 + lane];                    // f = 5..68
        if (lane == 0) vq += sp2[69];                // f = 69
        vq += __shfl_xor(vq, 1);
        vq += __shfl_xor(vq, 2);
        #pragma unroll
        for (int off = 4; off < 64; off <<= 1) {
            vp += __shfl_xor(vp, off);
            vq += __shfl_xor(vq, off);
        }
        if (lane < 4)  s_part[fr][lane] = vp;        // phi sum for n = lane
        if (lane == 0) s_part[fr][4]    = vq;        // psd sum
    }

    __syncthreads();   // barrier 3 of 3: s_part visible

    // phase 2: all threads form dcf = clamp(phi/psd) [* ratio], store out
    float* po = out + ((size_t)(b * NT + t0) * NF + f) * NNUL + n;
    const float* sdr = &s_dcf[0][tid];
    const float* spr = &s_part[0][0];
    const float* sqr = &s_psd[0][f];
    for (int fr = 0; fr < nf; ++fr) {
        const int t = t0 + fr;
        float dcfv = clamp01(sdr[0] * fast_rcp(sqr[0] + 1e-13f));
        float dcf2v = 0.f;
        if (extra) dcf2v = clamp01(sdr[4] * fast_rcp(sqr[1] + 1e-13f));
        if (t >= 1) {
            const float pre = spr[4];
            const float aft = spr[n];
            const float ratio = clamp01(aft * fast_rcp(pre + 1e-10f));
            dcfv = fast_sqrt(dcfv * ratio);
            if (extra) dcf2v = fast_sqrt(dcf2v * ratio);
        }
        *po = dcfv;
        if (extra) po[NNUL] = dcf2v;                 // f=256 slot
        po += NF * NNUL; sdr += 1028; spr += 25; sqr += 260;
    }
}

extern "C" void kernel_launch(void* const* d_in, const int* in_sizes, int n_in,
                              void* d_out, int out_size, void* d_ws, size_t ws_size,
                              hipStream_t stream) {
    const float* x       = (const float*)d_in[0];
    const int*   beam_id = (const int*)d_in[1];
    const float* targ_w  = (const float*)d_in[2];
    const float* null_w  = (const float*)d_in[3];
    float* out           = (float*)d_out;
    (void)d_ws; (void)ws_size;

    dcf_fused_kernel<<<dim3(NB * N_CHUNK), dim3(1024), 0, stream>>>(
        x, beam_id, targ_w, null_w, out);
}